// Round 8
// baseline (1791.142 us; speedup 1.0000x reference)
//
#include <hip/hip_runtime.h>

typedef short bf8 __attribute__((ext_vector_type(8)));
typedef float f32x4 __attribute__((ext_vector_type(4)));
typedef uint u32x4 __attribute__((ext_vector_type(4)));

static constexpr int BB = 256;   // batch
static constexpr int TT = 128;   // time
static constexpr int II = 512;   // input features
static constexpr int HH = 1024;  // hidden
static constexpr int OO = 512;   // fc out features
static constexpr int G4 = 4096;  // 4*H
static constexpr int NCONS = 128;  // consumer blocks (recurrence)
static constexpr int NPROD = 128;  // producer blocks (pre-GEMM)
static constexpr int RING = 2;     // pre ring slots

static constexpr size_t OUT_H = (size_t)BB * OO;
static constexpr size_t OUT_C = OUT_H + (size_t)BB * HH;
static constexpr size_t HBUF  = (size_t)BB * HH;

__device__ __forceinline__ float bf2f(ushort u) {
    unsigned v = ((unsigned)u) << 16;
    return __builtin_bit_cast(float, v);
}
__device__ __forceinline__ ushort f2bf(float f) {
    unsigned x = __builtin_bit_cast(unsigned, f);
    x = x + 0x7FFFu + ((x >> 16) & 1u);
    return (ushort)(x >> 16);
}
__device__ __forceinline__ float sigf(float x) { return 1.0f / (1.0f + __expf(-x)); }
__device__ __forceinline__ float tanhf_(float x) { return 2.0f * sigf(2.0f * x) - 1.0f; }

// ---- coherence-point (bypass) ops: validated in R4 ----
__device__ __forceinline__ void st_wt_short(const ushort* p, uint v) {
    asm volatile("global_store_short %0, %1, off sc0 sc1" :: "v"(p), "v"(v) : "memory");
}
__device__ __forceinline__ void st_wt_b128(const ushort* p, u32x4 v) {
    asm volatile("global_store_dwordx4 %0, %1, off sc0 sc1" :: "v"(p), "v"(v) : "memory");
}
__device__ __forceinline__ void ld_bp_ushort_issue(uint& dst, const ushort* p) {
    asm volatile("global_load_ushort %0, %1, off sc0 sc1" : "=v"(dst) : "v"(p) : "memory");
}
__device__ __forceinline__ void ld_bp_b128_issue(u32x4& dst, const ushort* p) {
    asm volatile("global_load_dwordx4 %0, %1, off sc0 sc1" : "=v"(dst) : "v"(p) : "memory");
}
__device__ __forceinline__ void wait_vm0() {
    asm volatile("s_waitcnt vmcnt(0)" ::: "memory");
    __builtin_amdgcn_sched_barrier(0);
}
#define WAITVM(N) do { asm volatile("s_waitcnt vmcnt(" #N ")" ::: "memory"); \
                       __builtin_amdgcn_sched_barrier(0); } while (0)

template <int SLP>
__device__ __forceinline__ int poll_ge(const int* p, int target) {
    int v;
    do {
        asm volatile("global_load_dword %0, %1, off sc0 sc1\n\ts_waitcnt vmcnt(0)"
                     : "=v"(v) : "v"(p) : "memory");
        if (v >= target) break;
        __builtin_amdgcn_s_sleep(SLP);
    } while (true);
    return v;
}

// ---- light group barrier (R4-validated): 64 blocks, store+poll, zero cache fences ----
__device__ __forceinline__ void lightbar(int* slots, int bg, int gen) {
    asm volatile("s_waitcnt vmcnt(0) lgkmcnt(0)" ::: "memory");
    __builtin_amdgcn_sched_barrier(0);
    __syncthreads();
    int tid = threadIdx.x;
    if (tid == 0)
        asm volatile("global_store_dword %0, %1, off sc0 sc1" :: "v"(slots + bg * 32), "v"(gen) : "memory");
    if (tid < 64) {
        const int* sp = slots + tid * 32;
        int v;
        do {
            asm volatile("global_load_dword %0, %1, off sc0 sc1\n\ts_waitcnt vmcnt(0)"
                         : "=v"(v) : "v"(sp) : "memory");
            if (v >= gen) break;
            __builtin_amdgcn_s_sleep(1);
        } while (true);
    }
    __syncthreads();
}

// flags layout: [0..2047] group0 slots, [2048..4095] group1 slots,
//               [4096..4223] seg_done, [4224..4351] seg_used
__global__ void k_init(int* flags) {
    int i = blockIdx.x * 256 + threadIdx.x;
    if (i < 4608) flags[i] = 0;
}

__global__ void k_cast(const float* __restrict__ src, ushort* __restrict__ dst, int n4) {
    int i = blockIdx.x * blockDim.x + threadIdx.x;
    int stride = gridDim.x * blockDim.x;
    for (; i < n4; i += stride) {
        float4 v = ((const float4*)src)[i];
        ushort4 o;
        o.x = f2bf(v.x); o.y = f2bf(v.y); o.z = f2bf(v.z); o.w = f2bf(v.w);
        ((ushort4*)dst)[i] = o;
    }
}

// permuted index p = j*64 + gate*16 + hc  ->  original row = gate*1024 + j*16 + hc
__global__ void k_prep_w(const float* __restrict__ w, ushort* __restrict__ wp,
                         const float* __restrict__ bi, const float* __restrict__ bh,
                         float* __restrict__ bp, int Kdim) {
    int p = blockIdx.x;
    int orig = ((p >> 4) & 3) * HH + ((p >> 6) << 4) + (p & 15);
    const float* src = w + (size_t)orig * Kdim;
    ushort* dst = wp + (size_t)p * Kdim;
    for (int k = threadIdx.x; k < Kdim; k += 256) dst[k] = f2bf(src[k]);
    if (threadIdx.x == 0 && bp) bp[p] = bi[orig] + bh[orig];
}

// ---- persistent kernel: blocks 0..127 = recurrence consumers (2 groups x 64),
//      blocks 128..255 = pre-GEMM producers feeding a RING of segments ----
__global__ __launch_bounds__(256) void k_main(
    const float* __restrict__ x, const ushort* __restrict__ wpih,
    const float* __restrict__ bp, ushort* __restrict__ pre,
    const ushort* __restrict__ wphh, ushort* __restrict__ hbf,
    float* __restrict__ dout, int* flags, int SEG) {
    __shared__ ushort wl[32 * 2048];  // consumers: W_hh slice (swizzled). producers: unused
    __shared__ ushort Al[64 * 32];    // producers: A stage
    __shared__ ushort Bl[128 * 32];   // producers: B stage

    int tid = threadIdx.x;
    int bid = blockIdx.x;
    int* seg_done = flags + 4096;
    int* seg_used = flags + 4224;
    int nseg = TT / SEG;
    size_t SEGEL = (size_t)SEG * BB * G4;

    int w = tid >> 6, l = tid & 63;
    int l15 = l & 15, kg = l >> 4;
    int wbase = ((l15 << 6) + (kg << 4)) ^ ((l15 & 7) << 4);

    if (bid >= NCONS) {
        // ================= PRODUCER =================
        int pid = bid - NCONS;
        int wm = w >> 1, wn = w & 1;
        int r0 = tid >> 2, kk = tid & 3;
        int sbyteA = ((r0 << 6) + (kk << 4)) ^ ((r0 & 7) << 4);
        int sbyteB1 = sbyteA + 4096;
        for (int sg = 0; sg < nseg; ++sg) {
            if (sg >= RING) {
                if (tid == 0) poll_ge<8>(seg_used + sg - RING, NCONS);
                __syncthreads();
            }
            ushort* sb = pre + (size_t)(sg % RING) * SEGEL;
            for (int i = 0; i < SEG; ++i) {
                int q = pid + (i << 7);
                int tm = q >> 5, tn = q & 31;
                int trel = tm >> 2, b0 = (tm & 3) << 6, n0 = tn << 7;
                int t = sg * SEG + trel;
                const float* xa = x + ((size_t)(b0 + r0) * TT + t) * II + (kk << 3);
                const ushort* gb0 = wpih + (size_t)(n0 + r0) * II + (kk << 3);
                const ushort* gb1 = gb0 + (size_t)64 * II;
                f32x4 acc[2][4];
#pragma unroll
                for (int mi = 0; mi < 2; ++mi)
#pragma unroll
                    for (int ni = 0; ni < 4; ++ni) acc[mi][ni] = f32x4{0.f, 0.f, 0.f, 0.f};
                float4 a0 = *(const float4*)xa;
                float4 a1 = *(const float4*)(xa + 4);
                uint4 b0v = *(const uint4*)gb0;
                uint4 b1v = *(const uint4*)gb1;
                for (int ko = 0; ko < 16; ++ko) {
                    union { ushort us[8]; uint4 v; } pa;
                    pa.us[0] = f2bf(a0.x); pa.us[1] = f2bf(a0.y); pa.us[2] = f2bf(a0.z); pa.us[3] = f2bf(a0.w);
                    pa.us[4] = f2bf(a1.x); pa.us[5] = f2bf(a1.y); pa.us[6] = f2bf(a1.z); pa.us[7] = f2bf(a1.w);
                    __syncthreads();
                    *(uint4*)((char*)Al + sbyteA) = pa.v;
                    *(uint4*)((char*)Bl + sbyteA) = b0v;
                    *(uint4*)((char*)Bl + sbyteB1) = b1v;
                    __syncthreads();
                    if (ko < 15) {
                        int k = (ko + 1) << 5;
                        a0 = *(const float4*)(xa + k);
                        a1 = *(const float4*)(xa + k + 4);
                        b0v = *(const uint4*)(gb0 + k);
                        b1v = *(const uint4*)(gb1 + k);
                    }
                    bf8 af[2], bv[4];
#pragma unroll
                    for (int mi = 0; mi < 2; ++mi)
                        af[mi] = *(const bf8*)((char*)Al + wm * 2048 + mi * 1024 + wbase);
#pragma unroll
                    for (int ni = 0; ni < 4; ++ni)
                        bv[ni] = *(const bf8*)((char*)Bl + wn * 4096 + ni * 1024 + wbase);
#pragma unroll
                    for (int mi = 0; mi < 2; ++mi)
#pragma unroll
                        for (int ni = 0; ni < 4; ++ni)
                            acc[mi][ni] = __builtin_amdgcn_mfma_f32_16x16x32_bf16(af[mi], bv[ni], acc[mi][ni], 0, 0, 0);
                }
#pragma unroll
                for (int ni = 0; ni < 4; ++ni) {
                    int col = n0 + wn * 64 + ni * 16 + l15;
                    float bias = bp[col];
#pragma unroll
                    for (int mi = 0; mi < 2; ++mi) {
                        int arow = b0 + wm * 32 + mi * 16 + (kg << 2);
#pragma unroll
                        for (int r = 0; r < 4; ++r)
                            st_wt_short(sb + ((size_t)trel * BB + arow + r) * G4 + col,
                                        (uint)f2bf(acc[mi][ni][r] + bias));
                    }
                }
            }
            asm volatile("s_waitcnt vmcnt(0)" ::: "memory");
            __builtin_amdgcn_sched_barrier(0);
            __syncthreads();
            if (tid == 0) atomicAdd(seg_done + sg, 1);
        }
        return;
    }

    // ================= CONSUMER =================
    int g = bid >> 6, j = bid & 63;
    int row0 = g << 7;                 // 128 batch rows per group
    int* slots = flags + g * 2048;
    int gen = 0;

    // load W_hh slice into LDS (swizzled)
    {
        const ushort* wsrc = wphh + (size_t)(j << 6) * HH;
        for (int s = 0; s < 32; ++s) {
            int cidx = (s << 8) + tid;
            int c = cidx >> 7;
            int kc = cidx & 127;
            uint4 v = *(const uint4*)(wsrc + (size_t)c * HH + (kc << 3));
            int byte = ((kc >> 2) << 12) + ((((c << 6) + ((kc & 3) << 4))) ^ ((c & 7) << 4));
            *(uint4*)((char*)wl + byte) = v;
        }
        // zero our h-slice in buffer 0: 128 rows x 16 cols
        int r = tid >> 1, hc = (tid & 1) << 3;
        u32x4 z = {0, 0, 0, 0};
        st_wt_b128(hbf + (size_t)(row0 + r) * HH + (j << 4) + hc, z);
    }

    int rw = row0 + (w << 5);          // wave's 32 rows
    const ushort* hA0 = hbf + (size_t)(rw + l15) * HH + (kg << 3);
    const ushort* hA1 = hbf + (size_t)(rw + 16 + l15) * HH + (kg << 3);
    int dr0 = rw + (kg << 2);
    int dr1 = rw + 16 + (kg << 2);
    int hcol = (j << 4) + l15;
    ushort* ho0 = hbf + (size_t)dr0 * HH + hcol;
    ushort* ho1 = hbf + (size_t)dr1 * HH + hcol;
    float creg[8] = {0.f, 0.f, 0.f, 0.f, 0.f, 0.f, 0.f, 0.f};

    gen++; lightbar(slots, j, gen);    // h0 zeros visible group-wide

    uint prn[32];
    for (int sg = 0; sg < nseg; ++sg) {
        ushort* sb = pre + (size_t)(sg % RING) * SEGEL;
        if (sg > 0 && tid == 0) atomicAdd(seg_used + sg - 1, 1);
        if (tid == 0) poll_ge<2>(seg_done + sg, NPROD);
        __syncthreads();
        // prefetch trel=0 pre slice
        {
            const ushort* pn0 = sb + (size_t)dr0 * G4 + (j << 6) + l15;
            const ushort* pn1 = sb + (size_t)dr1 * G4 + (j << 6) + l15;
#pragma unroll
            for (int ni = 0; ni < 4; ++ni)
#pragma unroll
                for (int r = 0; r < 4; ++r) {
                    ld_bp_ushort_issue(prn[ni * 4 + r], pn0 + (size_t)r * G4 + (ni << 4));
                    ld_bp_ushort_issue(prn[16 + ni * 4 + r], pn1 + (size_t)r * G4 + (ni << 4));
                }
            wait_vm0();
        }

        for (int trel = 0; trel < SEG; ++trel) {
            int t = sg * SEG + trel;
            const ushort* hr0 = hA0 + (size_t)(t & 1) * HBUF;
            const ushort* hr1 = hA1 + (size_t)(t & 1) * HBUF;
            // 2-deep double-buffered h pipeline: 4 clusters x 16 loads; <=32 in flight
            // (128 VGPRs) so no spills can corrupt the counted vmcnt windows.
            u32x4 x0[8], x1[8], y0[8], y1[8];

#define ISSUE8(B0, B1, C) \
            _Pragma("unroll") \
            for (int u = 0; u < 8; ++u) { \
                ld_bp_b128_issue(B0[u], hr0 + (((C) * 8 + u) << 5)); \
                ld_bp_b128_issue(B1[u], hr1 + (((C) * 8 + u) << 5)); \
            }
#define CONSUME8(B0, B1, C) \
            _Pragma("unroll") \
            for (int u = 0; u < 8; ++u) { \
                int ko = (C) * 8 + u; \
                bf8 a0 = __builtin_bit_cast(bf8, B0[u]); \
                bf8 a1 = __builtin_bit_cast(bf8, B1[u]); \
                _Pragma("unroll") \
                for (int ni = 0; ni < 4; ++ni) { \
                    bf8 b = *(const bf8*)((char*)wl + ko * 4096 + ni * 1024 + wbase); \
                    acc0[ni] = __builtin_amdgcn_mfma_f32_16x16x32_bf16(a0, b, acc0[ni], 0, 0, 0); \
                    acc1[ni] = __builtin_amdgcn_mfma_f32_16x16x32_bf16(a1, b, acc1[ni], 0, 0, 0); \
                } \
            }

            f32x4 acc0[4], acc1[4];
            ISSUE8(x0, x1, 0)          // 16 outstanding
            ISSUE8(y0, y1, 1)          // 32 outstanding
            // acc init from prefetched pre (VALU, overlaps load latency)
#pragma unroll
            for (int ni = 0; ni < 4; ++ni)
#pragma unroll
                for (int r = 0; r < 4; ++r) {
                    acc0[ni][r] = bf2f((ushort)prn[ni * 4 + r]);
                    acc1[ni][r] = bf2f((ushort)prn[16 + ni * 4 + r]);
                }
            WAITVM(16);                // cluster 0 done
            CONSUME8(x0, x1, 0)
            ISSUE8(x0, x1, 2)          // 32 outstanding
            WAITVM(16);                // cluster 1 done
            CONSUME8(y0, y1, 1)
            ISSUE8(y0, y1, 3)          // 32 outstanding
            WAITVM(16);                // cluster 2 done
            CONSUME8(x0, x1, 2)
            // prefetch next step's pre slice (dummy trel=0 reload at segment end).
            {
                int nrel = (trel + 1 < SEG) ? trel + 1 : 0;
                const ushort* pn0 = sb + ((size_t)nrel * BB + dr0) * G4 + (j << 6) + l15;
                const ushort* pn1 = sb + ((size_t)nrel * BB + dr1) * G4 + (j << 6) + l15;
#pragma unroll
                for (int ni = 0; ni < 4; ++ni)
#pragma unroll
                    for (int r = 0; r < 4; ++r) {
                        ld_bp_ushort_issue(prn[ni * 4 + r], pn0 + (size_t)r * G4 + (ni << 4));
                        ld_bp_ushort_issue(prn[16 + ni * 4 + r], pn1 + (size_t)r * G4 + (ni << 4));
                    }
            }                          // 16 (c3) + 32 (prn) = 48 outstanding
            WAITVM(32);                // cluster 3 done; prn drains at lightbar
            CONSUME8(y0, y1, 3)
#undef ISSUE8
#undef CONSUME8

            ushort* h0 = ho0 + (size_t)((t & 1) ^ 1) * HBUF;
            ushort* h1 = ho1 + (size_t)((t & 1) ^ 1) * HBUF;
            bool last = (t == TT - 1);
#pragma unroll
            for (int r = 0; r < 4; ++r) {
                float ig = sigf(acc0[0][r]);
                float fg = sigf(acc0[1][r]);
                float gg = tanhf_(acc0[2][r]);
                float og = sigf(acc0[3][r]);
                float c = fg * creg[r] + ig * gg;
                creg[r] = c;
                float h = og * tanhf_(c);
                st_wt_short(h0 + (size_t)r * HH, (uint)f2bf(h));
                if (last) {
                    dout[OUT_H + (size_t)(dr0 + r) * HH + hcol] = h;
                    dout[OUT_C + (size_t)(dr0 + r) * HH + hcol] = c;
                }
            }
#pragma unroll
            for (int r = 0; r < 4; ++r) {
                float ig = sigf(acc1[0][r]);
                float fg = sigf(acc1[1][r]);
                float gg = tanhf_(acc1[2][r]);
                float og = sigf(acc1[3][r]);
                float c = fg * creg[4 + r] + ig * gg;
                creg[4 + r] = c;
                float h = og * tanhf_(c);
                st_wt_short(h1 + (size_t)r * HH, (uint)f2bf(h));
                if (last) {
                    dout[OUT_H + (size_t)(dr1 + r) * HH + hcol] = h;
                    dout[OUT_C + (size_t)(dr1 + r) * HH + hcol] = c;
                }
            }
            gen++; lightbar(slots, j, gen);
        }
    }
}

// ---- FC: out = h @ W_fc^T + b_fc (final h is in hbf buffer 0) ----
__global__ __launch_bounds__(256) void k_fc(const ushort* __restrict__ hbf,
                                            const ushort* __restrict__ wfc,
                                            const float* __restrict__ bfc,
                                            float* __restrict__ out) {
    int tid = threadIdx.x;
    int b0 = (blockIdx.x >> 3) << 6;
    int n0 = (blockIdx.x & 7) << 6;
    int w = tid >> 6, l = tid & 63;
    int l15 = l & 15, kg = l >> 4;
    const ushort* ha = hbf + (size_t)(b0 + (w << 4) + l15) * HH + (kg << 3);
    f32x4 acc[4];
#pragma unroll
    for (int ni = 0; ni < 4; ++ni) acc[ni] = f32x4{0.f, 0.f, 0.f, 0.f};
    for (int ko = 0; ko < 32; ++ko) {
        bf8 a = *(const bf8*)(ha + (ko << 5));
#pragma unroll
        for (int ni = 0; ni < 4; ++ni) {
            bf8 b = *(const bf8*)(wfc + (size_t)(n0 + ni * 16 + l15) * HH + (ko << 5) + (kg << 3));
            acc[ni] = __builtin_amdgcn_mfma_f32_16x16x32_bf16(a, b, acc[ni], 0, 0, 0);
        }
    }
    int drow = b0 + (w << 4) + (kg << 2);
#pragma unroll
    for (int ni = 0; ni < 4; ++ni) {
        int col = n0 + ni * 16 + l15;
        float bias = bfc[col];
#pragma unroll
        for (int r = 0; r < 4; ++r)
            out[(size_t)(drow + r) * OO + col] = acc[ni][r] + bias;
    }
}

extern "C" void kernel_launch(void* const* d_in, const int* in_sizes, int n_in,
                              void* d_out, int out_size, void* d_ws, size_t ws_size,
                              hipStream_t stream) {
    const float* x   = (const float*)d_in[0];
    const float* Wih = (const float*)d_in[1];
    const float* Whh = (const float*)d_in[2];
    const float* bih = (const float*)d_in[3];
    const float* bhh = (const float*)d_in[4];
    const float* Wfc = (const float*)d_in[5];
    const float* bfc = (const float*)d_in[6];
    float* out = (float*)d_out;

    char* ws = (char*)d_ws;
    size_t off = 0;
    ushort* wpih = (ushort*)(ws + off); off += (size_t)G4 * II * 2;       // 4.2 MB
    ushort* wphh = (ushort*)(ws + off); off += (size_t)G4 * HH * 2;       // 8.4 MB
    ushort* wfcb = (ushort*)(ws + off); off += (size_t)OO * HH * 2;       // 1.0 MB
    float*  bp   = (float*)(ws + off);  off += (size_t)G4 * 4;            // 16 KB
    ushort* hbf  = (ushort*)(ws + off); off += (size_t)2 * BB * HH * 2;   // 1.0 MB
    int*    flags= (int*)(ws + off);    off += 4608 * 4;                  // 18 KB
    size_t fixed = off;
    int SEG = 16;
    while (SEG > 1 && fixed + (size_t)RING * SEG * BB * G4 * 2 > ws_size) SEG >>= 1;
    ushort* pre = (ushort*)(ws + off);  // RING * SEG * 2.1 MB

    k_init<<<18, 256, 0, stream>>>(flags);
    k_cast<<<256, 256, 0, stream>>>(Wfc, wfcb, OO * HH / 4);
    k_prep_w<<<G4, 256, 0, stream>>>(Wih, wpih, bih, bhh, bp, II);
    k_prep_w<<<G4, 256, 0, stream>>>(Whh, wphh, nullptr, nullptr, nullptr, HH);
    k_main<<<256, 256, 0, stream>>>(x, wpih, bp, pre, wphh, hbf, out, flags, SEG);
    k_fc<<<32, 256, 0, stream>>>(hbf, wfcb, bfc, out);
}

// Round 10
// 1515.008 us; speedup vs baseline: 1.1823x; 1.1823x over previous
//
#include <hip/hip_runtime.h>

typedef short bf8 __attribute__((ext_vector_type(8)));
typedef float f32x4 __attribute__((ext_vector_type(4)));
typedef uint u32x4 __attribute__((ext_vector_type(4)));

static constexpr int BB = 256;   // batch
static constexpr int TT = 128;   // time
static constexpr int II = 512;   // input features
static constexpr int HH = 1024;  // hidden
static constexpr int OO = 512;   // fc out features
static constexpr int G4 = 4096;  // 4*H

static constexpr size_t OUT_H = (size_t)BB * OO;
static constexpr size_t OUT_C = OUT_H + (size_t)BB * HH;
static constexpr size_t HBUF  = (size_t)BB * HH;   // one h buffer (elems)

__device__ __forceinline__ float bf2f(ushort u) {
    unsigned v = ((unsigned)u) << 16;
    return __builtin_bit_cast(float, v);
}
__device__ __forceinline__ ushort f2bf(float f) {
    unsigned x = __builtin_bit_cast(unsigned, f);
    x = x + 0x7FFFu + ((x >> 16) & 1u);
    return (ushort)(x >> 16);
}
__device__ __forceinline__ float sigf(float x) { return 1.0f / (1.0f + __expf(-x)); }
__device__ __forceinline__ float tanhf_(float x) { return 2.0f * sigf(2.0f * x) - 1.0f; }

// ---- write-through / bypass ops (R4-validated) ----
__device__ __forceinline__ void st_wt_short(const ushort* p, uint v) {
    asm volatile("global_store_short %0, %1, off sc0 sc1" :: "v"(p), "v"(v) : "memory");
}
__device__ __forceinline__ void st_wt_b64(const ushort* p, uint2 v) {
    asm volatile("global_store_dwordx2 %0, %1, off sc0 sc1" :: "v"(p), "v"(v) : "memory");
}
__device__ __forceinline__ void ld_bp_ushort_issue(uint& dst, const ushort* p) {
    asm volatile("global_load_ushort %0, %1, off sc0 sc1" : "=v"(dst) : "v"(p) : "memory");
}
__device__ __forceinline__ void ld_bp_b128_issue(u32x4& dst, const ushort* p) {
    asm volatile("global_load_dwordx4 %0, %1, off sc0 sc1" : "=v"(dst) : "v"(p) : "memory");
}
// cached load (h rotating buffers: first-touch-after-write makes this safe)
__device__ __forceinline__ void ld_c_b128_issue(u32x4& dst, const ushort* p) {
    asm volatile("global_load_dwordx4 %0, %1, off" : "=v"(dst) : "v"(p) : "memory");
}
__device__ __forceinline__ void wait_vm0() {
    asm volatile("s_waitcnt vmcnt(0)" ::: "memory");
    __builtin_amdgcn_sched_barrier(0);
}
#define WAITVM(N) do { asm volatile("s_waitcnt vmcnt(" #N ")" ::: "memory"); \
                       __builtin_amdgcn_sched_barrier(0); } while (0)

// ---- light group barrier: 64 blocks, store+poll, zero cache fences ----
__device__ __forceinline__ void lightbar(int* slots, int bg, int gen) {
    asm volatile("s_waitcnt vmcnt(0) lgkmcnt(0)" ::: "memory");
    __builtin_amdgcn_sched_barrier(0);
    __syncthreads();
    int tid = threadIdx.x;
    if (tid == 0)
        asm volatile("global_store_dword %0, %1, off sc0 sc1" :: "v"(slots + bg * 32), "v"(gen) : "memory");
    if (tid < 64) {
        const int* sp = slots + tid * 32;
        int v;
        do {
            asm volatile("global_load_dword %0, %1, off sc0 sc1\n\ts_waitcnt vmcnt(0)"
                         : "=v"(v) : "v"(sp) : "memory");
            if (v >= gen) break;
            __builtin_amdgcn_s_sleep(1);
        } while (true);
    }
    __syncthreads();
}

// flags: 4 groups x 64 slots x 32 pad
__global__ void k_init(int* flags) {
    int i = blockIdx.x * 256 + threadIdx.x;
    if (i < 8192) flags[i] = 0;
}

__global__ void k_cast(const float* __restrict__ src, ushort* __restrict__ dst, int n4) {
    int i = blockIdx.x * blockDim.x + threadIdx.x;
    int stride = gridDim.x * blockDim.x;
    for (; i < n4; i += stride) {
        float4 v = ((const float4*)src)[i];
        ushort4 o;
        o.x = f2bf(v.x); o.y = f2bf(v.y); o.z = f2bf(v.z); o.w = f2bf(v.w);
        ((ushort4*)dst)[i] = o;
    }
}

// permuted index p = j*64 + gate*16 + hc  ->  original row = gate*1024 + j*16 + hc
__global__ void k_prep_w(const float* __restrict__ w, ushort* __restrict__ wp,
                         const float* __restrict__ bi, const float* __restrict__ bh,
                         float* __restrict__ bp, int Kdim) {
    int p = blockIdx.x;
    int orig = ((p >> 4) & 3) * HH + ((p >> 6) << 4) + (p & 15);
    const float* src = w + (size_t)orig * Kdim;
    ushort* dst = wp + (size_t)p * Kdim;
    for (int k = threadIdx.x; k < Kdim; k += 256) dst[k] = f2bf(src[k]);
    if (threadIdx.x == 0 && bp) bp[p] = bi[orig] + bh[orig];
}

// ---- persistent phased kernel: 4 groups x 64 blocks; block = 64 rows x 64 permuted cols ----
// HMODE 0: h rotates through TT+1 buffers; reads CACHED (L2 serves the 64x broadcast),
//          writes write-through (MALL always fresh). First-touch-after-write => no staleness.
// HMODE 1: R4 fallback: 2 ping-pong buffers, bypass reads.
template <int HMODE>
__global__ __launch_bounds__(256) void k_main(
    const float* __restrict__ x, const ushort* __restrict__ wpih,
    const float* __restrict__ bp, ushort* __restrict__ pre,
    const ushort* __restrict__ wphh, ushort* __restrict__ hbf,
    float* __restrict__ dout, int* flags, int SEG) {
    __shared__ ushort wl[32 * 2048];  // W_hh slice (swizzled), 128 KiB
    __shared__ ushort Al[64 * 32];    // phase A stage
    __shared__ ushort Bl[128 * 32];

    int tid = threadIdx.x;
    int bid = blockIdx.x;
    int g = bid >> 6, j = bid & 63;
    int row0 = g << 6;
    int* slots = flags + g * 2048;
    int gen = 0;
    int nseg = TT / SEG;

    int w = tid >> 6, l = tid & 63;
    int l15 = l & 15, kg = l >> 4;
    int wbase = ((l15 << 6) + (kg << 4)) ^ ((l15 & 7) << 4);

    // load W_hh slice into LDS (swizzled); zero our slice of h buffer 0 (write-through)
    {
        const ushort* wsrc = wphh + (size_t)(j << 6) * HH;
        for (int s = 0; s < 32; ++s) {
            int cidx = (s << 8) + tid;
            int c = cidx >> 7;
            int kc = cidx & 127;
            uint4 v = *(const uint4*)(wsrc + (size_t)c * HH + (kc << 3));
            int byte = ((kc >> 2) << 12) + ((((c << 6) + ((kc & 3) << 4))) ^ ((c & 7) << 4));
            *(uint4*)((char*)wl + byte) = v;
        }
        int r = tid >> 2, hc = (tid & 3) << 2;
        uint2 z; z.x = 0; z.y = 0;
        st_wt_b64(hbf + (size_t)(row0 + r) * HH + (j << 4) + hc, z);
    }

    // phase A addressing
    int wm = w >> 1, wn = w & 1;
    int r0 = tid >> 2, kk = tid & 3;
    int sbyteA = ((r0 << 6) + (kk << 4)) ^ ((r0 & 7) << 4);
    int sbyteB1 = sbyteA + 4096;

    // phase B addressing
    const ushort* hbase = hbf + (size_t)(row0 + (w << 4) + l15) * HH + (kg << 3);
    int drow = row0 + (w << 4) + (kg << 2);
    int hcol = (j << 4) + l15;
    ushort* hobase = hbf + (size_t)drow * HH + hcol;
    const ushort* pbase = pre + (size_t)drow * G4 + (j << 6) + l15;
    float creg[4] = {0.f, 0.f, 0.f, 0.f};

    for (int sg = 0; sg < nseg; ++sg) {
        int t0 = sg * SEG;
        // ===== phase A: pre[t0..t0+SEG) for our 64 batch rows (tiles 64x128, K=512) =====
        int ntiles = SEG << 5;
        for (int q = j; q < ntiles; q += 64) {
            int trel = q >> 5;
            int t = t0 + trel;
            int n0 = (q & 31) << 7;
            const float* xa = x + ((size_t)(row0 + r0) * TT + t) * II + (kk << 3);
            const ushort* gb0 = wpih + (size_t)(n0 + r0) * II + (kk << 3);
            const ushort* gb1 = gb0 + (size_t)64 * II;
            f32x4 acc[2][4];
#pragma unroll
            for (int mi = 0; mi < 2; ++mi)
#pragma unroll
                for (int ni = 0; ni < 4; ++ni) acc[mi][ni] = f32x4{0.f, 0.f, 0.f, 0.f};
            float4 a0 = *(const float4*)xa;
            float4 a1 = *(const float4*)(xa + 4);
            uint4 b0v = *(const uint4*)gb0;
            uint4 b1v = *(const uint4*)gb1;
            for (int ko = 0; ko < 16; ++ko) {
                union { ushort us[8]; uint4 v; } pa;
                pa.us[0] = f2bf(a0.x); pa.us[1] = f2bf(a0.y); pa.us[2] = f2bf(a0.z); pa.us[3] = f2bf(a0.w);
                pa.us[4] = f2bf(a1.x); pa.us[5] = f2bf(a1.y); pa.us[6] = f2bf(a1.z); pa.us[7] = f2bf(a1.w);
                __syncthreads();
                *(uint4*)((char*)Al + sbyteA) = pa.v;
                *(uint4*)((char*)Bl + sbyteA) = b0v;
                *(uint4*)((char*)Bl + sbyteB1) = b1v;
                __syncthreads();
                if (ko < 15) {
                    int k = (ko + 1) << 5;
                    a0 = *(const float4*)(xa + k);
                    a1 = *(const float4*)(xa + k + 4);
                    b0v = *(const uint4*)(gb0 + k);
                    b1v = *(const uint4*)(gb1 + k);
                }
                bf8 af[2], bv[4];
#pragma unroll
                for (int mi = 0; mi < 2; ++mi)
                    af[mi] = *(const bf8*)((char*)Al + wm * 2048 + mi * 1024 + wbase);
#pragma unroll
                for (int ni = 0; ni < 4; ++ni)
                    bv[ni] = *(const bf8*)((char*)Bl + wn * 4096 + ni * 1024 + wbase);
#pragma unroll
                for (int mi = 0; mi < 2; ++mi)
#pragma unroll
                    for (int ni = 0; ni < 4; ++ni)
                        acc[mi][ni] = __builtin_amdgcn_mfma_f32_16x16x32_bf16(af[mi], bv[ni], acc[mi][ni], 0, 0, 0);
            }
#pragma unroll
            for (int ni = 0; ni < 4; ++ni) {
                int col = n0 + wn * 64 + ni * 16 + l15;
                float bias = bp[col];
#pragma unroll
                for (int mi = 0; mi < 2; ++mi) {
                    int arow = row0 + wm * 32 + mi * 16 + (kg << 2);
#pragma unroll
                    for (int r = 0; r < 4; ++r)
                        st_wt_short(pre + ((size_t)trel * BB + arow + r) * G4 + col,
                                    (uint)f2bf(acc[mi][ni][r] + bias));
                }
            }
        }
        gen++; lightbar(slots, j, gen);  // pre chunk + (sg==0) h0 zeros visible group-wide

        // ===== phase B: SEG recurrent steps =====
        uint prn[16];
#pragma unroll
        for (int ni = 0; ni < 4; ++ni)
#pragma unroll
            for (int r = 0; r < 4; ++r)
                ld_bp_ushort_issue(prn[ni * 4 + r], pbase + (size_t)r * G4 + (ni << 4));
        wait_vm0();

        for (int trel = 0; trel < SEG; ++trel) {
            int t = t0 + trel;
            int rb = HMODE ? (t & 1) : t;          // read buffer index
            int wb = HMODE ? ((t & 1) ^ 1) : (t + 1);  // write buffer index
            const ushort* hr = hbase + (size_t)rb * HBUF;
            u32x4 xv[8], yv[8];

#define ISSUE8(B, C) \
            _Pragma("unroll") \
            for (int u = 0; u < 8; ++u) { \
                if constexpr (HMODE == 0) ld_c_b128_issue(B[u], hr + (((C) * 8 + u) << 5)); \
                else ld_bp_b128_issue(B[u], hr + (((C) * 8 + u) << 5)); \
            }
#define CONSUME8(B, C) \
            _Pragma("unroll") \
            for (int u = 0; u < 8; ++u) { \
                int ko = (C) * 8 + u; \
                bf8 a = __builtin_bit_cast(bf8, B[u]); \
                _Pragma("unroll") \
                for (int ni = 0; ni < 4; ++ni) { \
                    bf8 b = *(const bf8*)((char*)wl + ko * 4096 + ni * 1024 + wbase); \
                    acc[ni] = __builtin_amdgcn_mfma_f32_16x16x32_bf16(a, b, acc[ni], 0, 0, 0); \
                } \
            }

            f32x4 acc[4];
            ISSUE8(xv, 0)              // 8 outstanding
            ISSUE8(yv, 1)              // 16
#pragma unroll
            for (int ni = 0; ni < 4; ++ni)
#pragma unroll
                for (int r = 0; r < 4; ++r) acc[ni][r] = bf2f((ushort)prn[ni * 4 + r]);
            WAITVM(8);                 // c0 done
            CONSUME8(xv, 0)
            ISSUE8(xv, 2)              // 16
            WAITVM(8);                 // c1 done
            CONSUME8(yv, 1)
            ISSUE8(yv, 3)              // 16
            WAITVM(8);                 // c2 done
            CONSUME8(xv, 2)
            {   // prefetch next step's pre slice (bypass; drains at lightbar)
                int nrel = (trel + 1 < SEG) ? trel + 1 : 0;
                const ushort* pnn = pre + ((size_t)nrel * BB + drow) * G4 + (j << 6) + l15;
#pragma unroll
                for (int ni = 0; ni < 4; ++ni)
#pragma unroll
                    for (int r = 0; r < 4; ++r)
                        ld_bp_ushort_issue(prn[ni * 4 + r], pnn + (size_t)r * G4 + (ni << 4));
            }                          // 8 (c3) + 16 (prn) = 24 outstanding
            WAITVM(16);                // c3 done (prn still in flight; drains at lightbar)
            CONSUME8(yv, 3)
#undef ISSUE8
#undef CONSUME8

            ushort* ho = hobase + (size_t)wb * HBUF;
            bool last = (t == TT - 1);
#pragma unroll
            for (int r = 0; r < 4; ++r) {
                float ig = sigf(acc[0][r]);
                float fg = sigf(acc[1][r]);
                float gg = tanhf_(acc[2][r]);
                float og = sigf(acc[3][r]);
                float c = fg * creg[r] + ig * gg;
                creg[r] = c;
                float h = og * tanhf_(c);
                st_wt_short(ho + (size_t)r * HH, (uint)f2bf(h));
                if (last) {
                    dout[OUT_H + (size_t)(drow + r) * HH + hcol] = h;
                    dout[OUT_C + (size_t)(drow + r) * HH + hcol] = c;
                }
            }
            gen++; lightbar(slots, j, gen);
        }
    }
}

// ---- FC: out = h_final @ W_fc^T + b_fc ----
__global__ __launch_bounds__(256) void k_fc(const ushort* __restrict__ hlast,
                                            const ushort* __restrict__ wfc,
                                            const float* __restrict__ bfc,
                                            float* __restrict__ out) {
    int tid = threadIdx.x;
    int b0 = (blockIdx.x >> 3) << 6;
    int n0 = (blockIdx.x & 7) << 6;
    int w = tid >> 6, l = tid & 63;
    int l15 = l & 15, kg = l >> 4;
    const ushort* ha = hlast + (size_t)(b0 + (w << 4) + l15) * HH + (kg << 3);
    f32x4 acc[4];
#pragma unroll
    for (int ni = 0; ni < 4; ++ni) acc[ni] = f32x4{0.f, 0.f, 0.f, 0.f};
    for (int ko = 0; ko < 32; ++ko) {
        bf8 a = *(const bf8*)(ha + (ko << 5));
#pragma unroll
        for (int ni = 0; ni < 4; ++ni) {
            bf8 b = *(const bf8*)(wfc + (size_t)(n0 + ni * 16 + l15) * HH + (ko << 5) + (kg << 3));
            acc[ni] = __builtin_amdgcn_mfma_f32_16x16x32_bf16(a, b, acc[ni], 0, 0, 0);
        }
    }
    int drow = b0 + (w << 4) + (kg << 2);
#pragma unroll
    for (int ni = 0; ni < 4; ++ni) {
        int col = n0 + ni * 16 + l15;
        float bias = bfc[col];
#pragma unroll
        for (int r = 0; r < 4; ++r)
            out[(size_t)(drow + r) * OO + col] = acc[ni][r] + bias;
    }
}

extern "C" void kernel_launch(void* const* d_in, const int* in_sizes, int n_in,
                              void* d_out, int out_size, void* d_ws, size_t ws_size,
                              hipStream_t stream) {
    const float* x   = (const float*)d_in[0];
    const float* Wih = (const float*)d_in[1];
    const float* Whh = (const float*)d_in[2];
    const float* bih = (const float*)d_in[3];
    const float* bhh = (const float*)d_in[4];
    const float* Wfc = (const float*)d_in[5];
    const float* bfc = (const float*)d_in[6];
    float* out = (float*)d_out;

    char* ws = (char*)d_ws;
    size_t off = 0;
    ushort* wpih = (ushort*)(ws + off); off += (size_t)G4 * II * 2;       // 4.2 MB
    ushort* wphh = (ushort*)(ws + off); off += (size_t)G4 * HH * 2;       // 8.4 MB
    ushort* wfcb = (ushort*)(ws + off); off += (size_t)OO * HH * 2;       // 1.0 MB
    float*  bp   = (float*)(ws + off);  off += (size_t)G4 * 4;            // 16 KB
    int*    flags= (int*)(ws + off);    off += 8192 * 4;                  // 32 KB
    size_t fixed = off;
    size_t HB2 = (size_t)BB * HH * 2;                                     // 512 KB

    // pick mode: prefer cached-rotating h (TT+1 buffers); fallback to bypass ping-pong
    int HMODE = 0, SEG = 16;
    size_t hsz = (size_t)(TT + 1) * HB2;                                  // 67.6 MB
    while (SEG > 1 && fixed + hsz + (size_t)SEG * BB * G4 * 2 > ws_size) SEG >>= 1;
    if (fixed + hsz + (size_t)SEG * BB * G4 * 2 > ws_size) {
        HMODE = 1; SEG = 16; hsz = 2 * HB2;
        while (SEG > 1 && fixed + hsz + (size_t)SEG * BB * G4 * 2 > ws_size) SEG >>= 1;
    }
    ushort* hbf = (ushort*)(ws + fixed);
    ushort* pre = (ushort*)(ws + fixed + hsz);
    const ushort* hlast = HMODE ? hbf : (hbf + (size_t)TT * HBUF);

    k_init<<<32, 256, 0, stream>>>(flags);
    k_cast<<<256, 256, 0, stream>>>(Wfc, wfcb, OO * HH / 4);
    k_prep_w<<<G4, 256, 0, stream>>>(Wih, wpih, bih, bhh, bp, II);
    k_prep_w<<<G4, 256, 0, stream>>>(Whh, wphh, nullptr, nullptr, nullptr, HH);
    if (HMODE == 0)
        k_main<0><<<256, 256, 0, stream>>>(x, wpih, bp, pre, wphh, hbf, out, flags, SEG);
    else
        k_main<1><<<256, 256, 0, stream>>>(x, wpih, bp, pre, wphh, hbf, out, flags, SEG);
    k_fc<<<32, 256, 0, stream>>>(hlast, wfcb, bfc, out);
}